// Round 4
// baseline (263.622 us; speedup 1.0000x reference)
//
#include <hip/hip_runtime.h>

typedef unsigned short u16;
typedef __bf16 bf16x8 __attribute__((ext_vector_type(8)));
typedef float f32x4 __attribute__((ext_vector_type(4)));
typedef float f32x16 __attribute__((ext_vector_type(16)));

#define AS1 __attribute__((address_space(1)))
#define AS3 __attribute__((address_space(3)))

static __device__ __forceinline__ u16 f2bf(float f) {
  union { float f; unsigned u; } v; v.f = f;
  unsigned r = (v.u + 0x7fff + ((v.u >> 16) & 1)) >> 16;
  return (u16)r;
}

// x [B][258] f32 -> hx [B][256] bf16, phase [B] float2
__global__ void prep_x_kernel(const float* __restrict__ x, u16* __restrict__ hx,
                              float2* __restrict__ phase, int B) {
  int i = blockIdx.x * blockDim.x + threadIdx.x;
  int total = B * 128;
  if (i < total) {
    int row = i >> 7, k2 = (i & 127);
    const float2 v = *reinterpret_cast<const float2*>(x + (size_t)row * 258 + k2 * 2);
    u16 a = f2bf(v.x), b = f2bf(v.y);
    *reinterpret_cast<unsigned*>(hx + (size_t)row * 256 + k2 * 2) =
        (unsigned)a | ((unsigned)b << 16);
  }
  if (i < B) {
    phase[i] = *reinterpret_cast<const float2*>(x + (size_t)i * 258 + 256);
  }
}

// w [2][K][N] f32 -> wt [2][N][K] bf16 (plain transposed layout, for layer 3)
__global__ void prep_w_kernel(const float* __restrict__ w, u16* __restrict__ wt,
                              int K, int N) {
  __shared__ u16 tile[64][65];
  int k0 = blockIdx.x * 64, n0 = blockIdx.y * 64, mode = blockIdx.z;
  const float* src = w + (size_t)mode * K * N;
  u16* dst = wt + (size_t)mode * N * K;
  int c = threadIdx.x & 63;
  int r4 = threadIdx.x >> 6;
#pragma unroll
  for (int i = 0; i < 16; ++i) {
    int r = r4 + i * 4;
    tile[r][c] = f2bf(src[(size_t)(k0 + r) * N + n0 + c]);
  }
  __syncthreads();
#pragma unroll
  for (int i = 0; i < 16; ++i) {
    int r = r4 + i * 4;  // n index offset
    dst[(size_t)(n0 + r) * K + k0 + c] = tile[c][r];
  }
}

// w [2][K][N] f32 -> wt' [2N][K] bf16, mode-interleaved by 32-col groups:
// n' = (n>>5)*64 + mode*32 + (n&31)
__global__ void prep_w_int_kernel(const float* __restrict__ w, u16* __restrict__ wt,
                                  int K, int N) {
  __shared__ u16 tile[64][65];
  int k0 = blockIdx.x * 64, n0 = blockIdx.y * 64, mode = blockIdx.z;
  const float* src = w + (size_t)mode * K * N;
  int c = threadIdx.x & 63;
  int r4 = threadIdx.x >> 6;
#pragma unroll
  for (int i = 0; i < 16; ++i) {
    int r = r4 + i * 4;
    tile[r][c] = f2bf(src[(size_t)(k0 + r) * N + n0 + c]);
  }
  __syncthreads();
#pragma unroll
  for (int i = 0; i < 16; ++i) {
    int n = n0 + r4 + i * 4;
    int np = ((n >> 5) << 6) + (mode << 5) + (n & 31);
    wt[(size_t)np * K + k0 + c] = tile[c][r4 + i * 4];
  }
}

// ---------------------------------------------------------------------------
// 256x256-tile ring-buffered GEMM over N' = 2N (mode-interleaved by 32 cols),
// 32x32x16 MFMA. A [M][K] bf16; Wt [N'][K] bf16; out [M][N'/2] bf16.
// 8 waves (2Mx4N), per-wave 128x64 (4 mfrags x 2 nfrags of 32x32), BK=32,
// ring of 4 LDS buffers (128 KiB), st_16x32 swizzle, counted vmcnt(8).
// ---------------------------------------------------------------------------
template <bool ELU_STORE>
__global__ __launch_bounds__(512, 2) void gemm_ring32(
    const u16* __restrict__ A, const u16* __restrict__ Wt,
    const float* __restrict__ bias, const float2* __restrict__ phase,
    u16* __restrict__ out, int K, int Np) {
  __shared__ u16 lds[4][2][8192];  // [ring buf][A|B][256 rows x 32 cols swz]
  const int tnc = Np >> 8;
  const int nwg = gridDim.x;
  int id = blockIdx.x;
  const int cpx = nwg >> 3;  // nwg % 8 == 0 (1024)
  id = (id & 7) * cpx + (id >> 3);
  const int m0 = (id / tnc) * 256;
  const int n0 = (id % tnc) * 256;
  const int t = threadIdx.x;
  const int lane = t & 63;
  const int wave = t >> 6;
  const int wr = wave >> 2, wc = wave & 3;
  const int l31 = lane & 31, lhi = lane >> 5;

  // 32x32x16 fragment read: lane reads 16B at (row = frag*32 + l31,
  // col = kk*16 + lhi*8) from swizzled [16r x 32c] subtiled LDS.
  // subtile = row>>4; within: (row&15)*64B + swizzled-col*2B.
  const int sub_l = ((l31 >> 4) & 1) * 1024 + (l31 & 15) * 64;
  int cx[2];
#pragma unroll
  for (int kk = 0; kk < 2; ++kk)
    cx[kk] = (((kk * 16 + lhi * 8) ^ (((l31 >> 3) & 1) << 4)) << 1);

  // staging decode: chunk q = ld*512 + t covers LDS bytes q*16..+15 (linear);
  // inverse st_16x32 swizzle on the global source column:
  int soff[2];
#pragma unroll
  for (int ld = 0; ld < 2; ++ld) {
    int e = (ld * 512 + t) * 8;
    int st = e >> 9;
    int rl = (e >> 5) & 15;
    int c = e & 31;
    int c0 = c ^ (((rl >> 3) & 1) << 4);
    soff[ld] = (st * 16 + rl) * K + c0;
  }
  const u16* Abase = A + (size_t)m0 * K;
  const u16* Bbase = Wt + (size_t)n0 * K;

  f32x16 acc[4][2] = {};
  const int NT = K >> 5;

  auto stage = [&](int bb, int tile) {
    const int kt = tile << 5;
#pragma unroll
    for (int ld = 0; ld < 2; ++ld)
      __builtin_amdgcn_global_load_lds(
          (const AS1 void*)(Abase + kt + soff[ld]),
          (AS3 void*)(&lds[bb][0][(ld * 512 + t) * 8]), 16, 0, 0);
#pragma unroll
    for (int ld = 0; ld < 2; ++ld)
      __builtin_amdgcn_global_load_lds(
          (const AS1 void*)(Bbase + kt + soff[ld]),
          (AS3 void*)(&lds[bb][1][(ld * 512 + t) * 8]), 16, 0, 0);
  };

#define BAR()                    \
  asm volatile("" ::: "memory"); \
  __builtin_amdgcn_s_barrier();  \
  asm volatile("" ::: "memory");

  // A-frag (mfrag m in wave's 128-row half, kk) at subtile (wr*8 + m*2 + ..):
#define LOADA(mh)                                                            \
  _Pragma("unroll") for (int m = 0; m < 2; ++m)                              \
  _Pragma("unroll") for (int kk = 0; kk < 2; ++kk)                           \
      af[m][kk] = *(const bf16x8*)(lA +                                      \
          ((wr * 8 + ((mh)*2 + m) * 2) << 10) + sub_l + cx[kk]);
#define LOADB()                                                              \
  _Pragma("unroll") for (int n = 0; n < 2; ++n)                              \
  _Pragma("unroll") for (int kk = 0; kk < 2; ++kk)                           \
      bfr[n][kk] = *(const bf16x8*)(lB +                                     \
          ((wc * 4 + n * 2) << 10) + sub_l + cx[kk]);
#define MFMAH(mh)                                                            \
  __builtin_amdgcn_s_setprio(1);                                             \
  _Pragma("unroll") for (int m = 0; m < 2; ++m)                              \
  _Pragma("unroll") for (int n = 0; n < 2; ++n)                              \
  _Pragma("unroll") for (int kk = 0; kk < 2; ++kk)                           \
      acc[(mh)*2 + m][n] = __builtin_amdgcn_mfma_f32_32x32x16_bf16(          \
          af[m][kk], bfr[n][kk], acc[(mh)*2 + m][n], 0, 0, 0);               \
  __builtin_amdgcn_s_setprio(0);

  // prologue: 3 tiles deep
  stage(0, 0);
  stage(1, 1);
  stage(2, 2);
  asm volatile("s_waitcnt vmcnt(8)" ::: "memory");  // tile 0 landed
  BAR();

  for (int tt = 0; tt < NT; ++tt) {
    const char* lA = (const char*)&lds[tt & 3][0][0];
    const char* lB = (const char*)&lds[tt & 3][1][0];
    bf16x8 af[2][2], bfr[2][2];
    // phase 0: mfrags 0,1 + all B; prefetch tile tt+3 into buf (tt-1)&3
    LOADA(0);
    LOADB();
    if (tt + 3 < NT) stage((tt + 3) & 3, tt + 3);
    BAR();
    MFMAH(0);
    BAR();
    // phase 1: mfrags 2,3
    LOADA(1);
    BAR();
    MFMAH(1);
    // counted wait: retire only tile tt+1's 4 loads (8 = tiles tt+2,tt+3 stay)
    asm volatile("s_waitcnt vmcnt(8)" ::: "memory");
    BAR();
  }
#undef LOADA
#undef LOADB
#undef MFMAH

  // epilogue: 32x32 C/D map: col = lane&31, row = (reg&3)+8*(reg>>2)+4*lhi.
  // nfrag 0 = mode0, nfrag 1 = mode1 over the SAME 32 real cols.
  const int Nreal = Np >> 1;
  const int col = (n0 >> 1) + wc * 32 + l31;
  const float bias0 = bias[col];
  const float bias1 = bias[Nreal + col];
#pragma unroll
  for (int m = 0; m < 4; ++m) {
#pragma unroll
    for (int rg = 0; rg < 16; ++rg) {
      int grow = m0 + wr * 128 + m * 32 + (rg & 3) + 8 * (rg >> 2) + 4 * lhi;
      float2 ph = phase[grow];
      float v = ph.x * (acc[m][0][rg] + bias0) + ph.y * (acc[m][1][rg] + bias1);
      if (ELU_STORE) v = v > 0.f ? v : (__expf(v) - 1.f);
      out[(size_t)grow * Nreal + col] = f2bf(v);
    }
  }
#undef BAR
}

// Dual-mode GEMM (layer 3, small N): acc_i = A @ W_i^T, blended epilogue, f32 out
template <int BM, int BN, int WM, int WN, bool ELU_BF16>
__launch_bounds__(256, 2) __global__
void gemm_dualmode(const u16* __restrict__ A, const u16* __restrict__ WT,
                   const float* __restrict__ bias, const float2* __restrict__ phase,
                   void* __restrict__ out, int K, int N) {
  constexpr int MF = WM / 16, NF = WN / 16;
  __shared__ u16 ldsA[BM * 32];
  __shared__ u16 ldsB[2][BN * 32];
  const int m0 = blockIdx.x * BM;
  const int n0 = blockIdx.y * BN;
  const int t = threadIdx.x;
  const int wave = t >> 6, lane = t & 63;
  constexpr int NWC = BN / WN;
  const int wr = wave / NWC, wc = wave % NWC;
  const int lr = lane & 15, ks = lane >> 4;

  f32x4 acc[2][MF][NF] = {};

  for (int kt = 0; kt < K; kt += 32) {
#pragma unroll
    for (int i = 0; i < BM / 64; ++i) {
      int tt = t + i * 256;
      int r = tt >> 2, c8 = (tt & 3) * 8;
      __builtin_amdgcn_global_load_lds(
          (const AS1 void*)(A + (size_t)(m0 + r) * K + kt + c8),
          (AS3 void*)(ldsA + (size_t)tt * 8), 16, 0, 0);
    }
#pragma unroll
    for (int md = 0; md < 2; ++md) {
#pragma unroll
      for (int i = 0; i < BN / 64; ++i) {
        int tt = t + i * 256;
        int r = tt >> 2, c8 = (tt & 3) * 8;
        __builtin_amdgcn_global_load_lds(
            (const AS1 void*)(WT + (size_t)md * N * K + (size_t)(n0 + r) * K + kt + c8),
            (AS3 void*)(ldsB[md] + (size_t)tt * 8), 16, 0, 0);
      }
    }
    __syncthreads();

    bf16x8 af[MF], b0f[NF], b1f[NF];
#pragma unroll
    for (int m = 0; m < MF; ++m)
      af[m] = *reinterpret_cast<const bf16x8*>(&ldsA[(wr * WM + m * 16 + lr) * 32 + ks * 8]);
#pragma unroll
    for (int n = 0; n < NF; ++n) {
      b0f[n] = *reinterpret_cast<const bf16x8*>(&ldsB[0][(wc * WN + n * 16 + lr) * 32 + ks * 8]);
      b1f[n] = *reinterpret_cast<const bf16x8*>(&ldsB[1][(wc * WN + n * 16 + lr) * 32 + ks * 8]);
    }
#pragma unroll
    for (int m = 0; m < MF; ++m) {
#pragma unroll
      for (int n = 0; n < NF; ++n) {
        acc[0][m][n] = __builtin_amdgcn_mfma_f32_16x16x32_bf16(af[m], b0f[n], acc[0][m][n], 0, 0, 0);
        acc[1][m][n] = __builtin_amdgcn_mfma_f32_16x16x32_bf16(af[m], b1f[n], acc[1][m][n], 0, 0, 0);
      }
    }
    __syncthreads();
  }

#pragma unroll
  for (int m = 0; m < MF; ++m) {
#pragma unroll
    for (int j = 0; j < 4; ++j) {
      int grow = m0 + wr * WM + m * 16 + ks * 4 + j;
      float2 ph = phase[grow];
#pragma unroll
      for (int n = 0; n < NF; ++n) {
        int gcol = n0 + wc * WN + n * 16 + lr;
        float v = ph.x * (acc[0][m][n][j] + bias[gcol]) +
                  ph.y * (acc[1][m][n][j] + bias[N + gcol]);
        if (ELU_BF16) {
          v = v > 0.f ? v : (__expf(v) - 1.f);
          ((u16*)out)[(size_t)grow * N + gcol] = f2bf(v);
        } else {
          ((float*)out)[(size_t)grow * N + gcol] = v;
        }
      }
    }
  }
}

extern "C" void kernel_launch(void* const* d_in, const int* in_sizes, int n_in,
                              void* d_out, int out_size, void* d_ws, size_t ws_size,
                              hipStream_t stream) {
  const float* x  = (const float*)d_in[0];
  const float* w1 = (const float*)d_in[1];
  const float* b1 = (const float*)d_in[2];
  const float* w2 = (const float*)d_in[3];
  const float* b2 = (const float*)d_in[4];
  const float* w3 = (const float*)d_in[5];
  const float* b3 = (const float*)d_in[6];
  float* out = (float*)d_out;
  const int B = 32768, DIN = 256, H = 1024, DOUT = 64;

  char* ws = (char*)d_ws;
  u16* W1Ti = (u16*)ws;    ws += (size_t)2 * H * DIN * 2;   // [2048][256]
  u16* W2Ti = (u16*)ws;    ws += (size_t)2 * H * H * 2;     // [2048][1024]
  u16* W3T = (u16*)ws;     ws += (size_t)2 * DOUT * H * 2;  // [2][64][1024]
  float2* phase = (float2*)ws; ws += (size_t)B * 8;
  u16* hx = (u16*)ws;      ws += (size_t)B * DIN * 2;
  u16* h1 = (u16*)ws;      ws += (size_t)B * H * 2;
  u16* h2 = (u16*)ws;      ws += (size_t)B * H * 2;

  prep_x_kernel<<<(B * 128 + 255) / 256, 256, 0, stream>>>(x, hx, phase, B);
  prep_w_int_kernel<<<dim3(DIN / 64, H / 64, 2), 256, 0, stream>>>(w1, W1Ti, DIN, H);
  prep_w_int_kernel<<<dim3(H / 64, H / 64, 2), 256, 0, stream>>>(w2, W2Ti, H, H);
  prep_w_kernel<<<dim3(H / 64, DOUT / 64, 2), 256, 0, stream>>>(w3, W3T, H, DOUT);

  const int nwg = (B / 256) * (2 * H / 256);  // 128 * 8 = 1024
  gemm_ring32<true><<<nwg, 512, 0, stream>>>(hx, W1Ti, b1, phase, h1, DIN, 2 * H);
  gemm_ring32<true><<<nwg, 512, 0, stream>>>(h1, W2Ti, b2, phase, h2, H, 2 * H);
  gemm_dualmode<128, 64, 64, 32, false>
      <<<dim3(B / 128, DOUT / 64), 256, 0, stream>>>(h2, W3T, b3, phase, out, H, DOUT);
}

// Round 5
// 229.787 us; speedup vs baseline: 1.1472x; 1.1472x over previous
//
#include <hip/hip_runtime.h>

typedef unsigned short u16;
typedef __bf16 bf16x8 __attribute__((ext_vector_type(8)));
typedef float f32x4 __attribute__((ext_vector_type(4)));

#define AS1 __attribute__((address_space(1)))
#define AS3 __attribute__((address_space(3)))

static __device__ __forceinline__ u16 f2bf(float f) {
  union { float f; unsigned u; } v; v.f = f;
  unsigned r = (v.u + 0x7fff + ((v.u >> 16) & 1)) >> 16;
  return (u16)r;
}

// x [B][258] f32 -> hx [B][256] bf16, phase [B] float2
__global__ void prep_x_kernel(const float* __restrict__ x, u16* __restrict__ hx,
                              float2* __restrict__ phase, int B) {
  int i = blockIdx.x * blockDim.x + threadIdx.x;
  int total = B * 128;
  if (i < total) {
    int row = i >> 7, k2 = (i & 127);
    const float2 v = *reinterpret_cast<const float2*>(x + (size_t)row * 258 + k2 * 2);
    u16 a = f2bf(v.x), b = f2bf(v.y);
    *reinterpret_cast<unsigned*>(hx + (size_t)row * 256 + k2 * 2) =
        (unsigned)a | ((unsigned)b << 16);
  }
  if (i < B) {
    phase[i] = *reinterpret_cast<const float2*>(x + (size_t)i * 258 + 256);
  }
}

// w [2][K][N] f32 -> wt [2][N][K] bf16 (plain transposed layout, for layer 3)
__global__ void prep_w_kernel(const float* __restrict__ w, u16* __restrict__ wt,
                              int K, int N) {
  __shared__ u16 tile[64][65];
  int k0 = blockIdx.x * 64, n0 = blockIdx.y * 64, mode = blockIdx.z;
  const float* src = w + (size_t)mode * K * N;
  u16* dst = wt + (size_t)mode * N * K;
  int c = threadIdx.x & 63;
  int r4 = threadIdx.x >> 6;
#pragma unroll
  for (int i = 0; i < 16; ++i) {
    int r = r4 + i * 4;
    tile[r][c] = f2bf(src[(size_t)(k0 + r) * N + n0 + c]);
  }
  __syncthreads();
#pragma unroll
  for (int i = 0; i < 16; ++i) {
    int r = r4 + i * 4;  // n index offset
    dst[(size_t)(n0 + r) * K + k0 + c] = tile[c][r];
  }
}

// w [2][K][N] f32 -> wt' [2N][K] bf16, mode-interleaved by 16-col groups:
// n' = (n>>4)*32 + mode*16 + (n&15)
__global__ void prep_w_int_kernel(const float* __restrict__ w, u16* __restrict__ wt,
                                  int K, int N) {
  __shared__ u16 tile[64][65];
  int k0 = blockIdx.x * 64, n0 = blockIdx.y * 64, mode = blockIdx.z;
  const float* src = w + (size_t)mode * K * N;
  int c = threadIdx.x & 63;
  int r4 = threadIdx.x >> 6;
#pragma unroll
  for (int i = 0; i < 16; ++i) {
    int r = r4 + i * 4;
    tile[r][c] = f2bf(src[(size_t)(k0 + r) * N + n0 + c]);
  }
  __syncthreads();
#pragma unroll
  for (int i = 0; i < 16; ++i) {
    int n = n0 + r4 + i * 4;
    int np = ((n >> 4) << 5) + (mode << 4) + (n & 15);
    wt[(size_t)np * K + k0 + c] = tile[c][r4 + i * 4];
  }
}

// ---------------------------------------------------------------------------
// 256x256-tile ring-buffered GEMM over N' = 2N (mode-interleaved weights).
// A [M][K] bf16; Wt [N'][K] bf16; out [M][N'/2] bf16 (phase-blended, opt ELU).
// 8 waves (2Mx4N), per-wave 128x64, BK=32, ring of 4 LDS buffers (128 KiB),
// st_16x32 swizzle, counted vmcnt(8), ONE barrier per K-tile, and ds_reads
// software-pipelined across the barrier so they overlap MFMA.
// ---------------------------------------------------------------------------
template <bool ELU_STORE>
__global__ __launch_bounds__(512, 2) void gemm_ring(
    const u16* __restrict__ A, const u16* __restrict__ Wt,
    const float* __restrict__ bias, const float2* __restrict__ phase,
    u16* __restrict__ out, int K, int Np) {
  __shared__ u16 lds[4][2][8192];  // [ring buf][A|B][256 rows x 32 cols swz]
  const int tnc = Np >> 8;
  const int nwg = gridDim.x;
  int id = blockIdx.x;
  const int cpx = nwg >> 3;  // nwg % 8 == 0 (1024)
  id = (id & 7) * cpx + (id >> 3);
  const int m0 = (id / tnc) * 256;
  const int n0 = (id % tnc) * 256;
  const int t = threadIdx.x;
  const int lane = t & 63;
  const int wave = t >> 6;
  const int wr = wave >> 2, wc = wave & 3;
  const int lr = lane & 15, ks = lane >> 4;
  // swizzled byte offset within a 1024B (16row x 32col) subtile:
  const int cswz = lr * 64 + (((ks * 8) ^ ((lr >> 3) << 4)) << 1);

  // staging decode: chunk q = ld*512 + t covers LDS bytes q*16..+15 (linear);
  // inverse st_16x32 swizzle on the global source column:
  int soff[2];
#pragma unroll
  for (int ld = 0; ld < 2; ++ld) {
    int e = (ld * 512 + t) * 8;
    int st = e >> 9;
    int rl = (e >> 5) & 15;
    int c = e & 31;
    int c0 = c ^ (((rl >> 3) & 1) << 4);
    soff[ld] = (st * 16 + rl) * K + c0;
  }
  const u16* Abase = A + (size_t)m0 * K;
  const u16* Bbase = Wt + (size_t)n0 * K;

  f32x4 acc[8][4] = {};
  const int NT = K >> 5;

  auto stage = [&](int bb, int tile) {
    const int kt = tile << 5;
#pragma unroll
    for (int ld = 0; ld < 2; ++ld)
      __builtin_amdgcn_global_load_lds(
          (const AS1 void*)(Abase + kt + soff[ld]),
          (AS3 void*)(&lds[bb][0][(ld * 512 + t) * 8]), 16, 0, 0);
#pragma unroll
    for (int ld = 0; ld < 2; ++ld)
      __builtin_amdgcn_global_load_lds(
          (const AS1 void*)(Bbase + kt + soff[ld]),
          (AS3 void*)(&lds[bb][1][(ld * 512 + t) * 8]), 16, 0, 0);
  };

#define BAR()                    \
  asm volatile("" ::: "memory"); \
  __builtin_amdgcn_s_barrier();  \
  asm volatile("" ::: "memory");

#define LOADA0(buf)                               \
  _Pragma("unroll") for (int m = 0; m < 4; ++m)   \
      af0[m] = *(const bf16x8*)((const char*)&lds[buf][0][0] + (((wr * 8 + m) << 10) + cswz));
#define LOADA1(buf)                               \
  _Pragma("unroll") for (int m = 0; m < 4; ++m)   \
      af1[m] = *(const bf16x8*)((const char*)&lds[buf][0][0] + (((wr * 8 + 4 + m) << 10) + cswz));
#define LOADB(buf)                                \
  _Pragma("unroll") for (int n = 0; n < 4; ++n)   \
      bfr[n] = *(const bf16x8*)((const char*)&lds[buf][1][0] + (((wc * 4 + n) << 10) + cswz));
#define MFMAH(mh, AF)                                                   \
  __builtin_amdgcn_s_setprio(1);                                        \
  _Pragma("unroll") for (int m = 0; m < 4; ++m)                         \
  _Pragma("unroll") for (int n = 0; n < 4; ++n)                         \
      acc[(mh)*4 + m][n] = __builtin_amdgcn_mfma_f32_16x16x32_bf16(     \
          AF[m], bfr[n], acc[(mh)*4 + m][n], 0, 0, 0);                  \
  __builtin_amdgcn_s_setprio(0);

  bf16x8 af0[4], af1[4], bfr[4];

  // prologue: 3 tiles deep; tile 0 landed after vmcnt(8)
  stage(0, 0);
  stage(1, 1);
  stage(2, 2);
  asm volatile("s_waitcnt vmcnt(8)" ::: "memory");
  BAR();
  LOADA0(0);
  LOADB(0);

  for (int tt = 0; tt < NT; ++tt) {
    const int b = tt & 3;
    // issue second-half A reads; they fly under MFMAH(0)
    LOADA1(b);
    MFMAH(0, af0);                  // waits af0/bfr (issued pre-barrier)
    if (tt + 3 < NT) stage((tt + 3) & 3, tt + 3);
    // retire tile tt+1's 4 loads (tiles tt+2, tt+3 = 8 stay in flight)
    asm volatile("s_waitcnt vmcnt(8)" ::: "memory");
    MFMAH(1, af1);                  // waits af1 (overlapped with MFMAH(0))
    BAR();
    // issue next tile's first-half reads; they fly across the loop edge
    if (tt + 1 < NT) {
      const int b2 = (tt + 1) & 3;
      LOADA0(b2);
      LOADB(b2);
    }
  }
#undef LOADA0
#undef LOADA1
#undef LOADB
#undef MFMAH

  // epilogue: blend mode pairs with phase, add bias, optional ELU, bf16 store
  const int Nreal = Np >> 1;
  const int colbase = (n0 + wc * 64) >> 1;
  float bias0[2], bias1[2];
#pragma unroll
  for (int pj = 0; pj < 2; ++pj) {
    int ncol = colbase + pj * 16 + lr;
    bias0[pj] = bias[ncol];
    bias1[pj] = bias[Nreal + ncol];
  }
#pragma unroll
  for (int m = 0; m < 8; ++m) {
#pragma unroll
    for (int j = 0; j < 4; ++j) {
      int grow = m0 + wr * 128 + m * 16 + ks * 4 + j;
      float2 ph = phase[grow];
#pragma unroll
      for (int pj = 0; pj < 2; ++pj) {
        int ncol = colbase + pj * 16 + lr;
        float v = ph.x * (acc[m][pj * 2 + 0][j] + bias0[pj]) +
                  ph.y * (acc[m][pj * 2 + 1][j] + bias1[pj]);
        if (ELU_STORE) v = v > 0.f ? v : (__expf(v) - 1.f);
        out[(size_t)grow * Nreal + ncol] = f2bf(v);
      }
    }
  }
#undef BAR
}

// Dual-mode GEMM (layer 3, small N): acc_i = A @ W_i^T, blended epilogue, f32 out
template <int BM, int BN, int WM, int WN, bool ELU_BF16>
__launch_bounds__(256, 2) __global__
void gemm_dualmode(const u16* __restrict__ A, const u16* __restrict__ WT,
                   const float* __restrict__ bias, const float2* __restrict__ phase,
                   void* __restrict__ out, int K, int N) {
  constexpr int MF = WM / 16, NF = WN / 16;
  __shared__ u16 ldsA[BM * 32];
  __shared__ u16 ldsB[2][BN * 32];
  const int m0 = blockIdx.x * BM;
  const int n0 = blockIdx.y * BN;
  const int t = threadIdx.x;
  const int wave = t >> 6, lane = t & 63;
  constexpr int NWC = BN / WN;
  const int wr = wave / NWC, wc = wave % NWC;
  const int lr = lane & 15, ks = lane >> 4;

  f32x4 acc[2][MF][NF] = {};

  for (int kt = 0; kt < K; kt += 32) {
#pragma unroll
    for (int i = 0; i < BM / 64; ++i) {
      int tt = t + i * 256;
      int r = tt >> 2, c8 = (tt & 3) * 8;
      __builtin_amdgcn_global_load_lds(
          (const AS1 void*)(A + (size_t)(m0 + r) * K + kt + c8),
          (AS3 void*)(ldsA + (size_t)tt * 8), 16, 0, 0);
    }
#pragma unroll
    for (int md = 0; md < 2; ++md) {
#pragma unroll
      for (int i = 0; i < BN / 64; ++i) {
        int tt = t + i * 256;
        int r = tt >> 2, c8 = (tt & 3) * 8;
        __builtin_amdgcn_global_load_lds(
            (const AS1 void*)(WT + (size_t)md * N * K + (size_t)(n0 + r) * K + kt + c8),
            (AS3 void*)(ldsB[md] + (size_t)tt * 8), 16, 0, 0);
      }
    }
    __syncthreads();

    bf16x8 af[MF], b0f[NF], b1f[NF];
#pragma unroll
    for (int m = 0; m < MF; ++m)
      af[m] = *reinterpret_cast<const bf16x8*>(&ldsA[(wr * WM + m * 16 + lr) * 32 + ks * 8]);
#pragma unroll
    for (int n = 0; n < NF; ++n) {
      b0f[n] = *reinterpret_cast<const bf16x8*>(&ldsB[0][(wc * WN + n * 16 + lr) * 32 + ks * 8]);
      b1f[n] = *reinterpret_cast<const bf16x8*>(&ldsB[1][(wc * WN + n * 16 + lr) * 32 + ks * 8]);
    }
#pragma unroll
    for (int m = 0; m < MF; ++m) {
#pragma unroll
      for (int n = 0; n < NF; ++n) {
        acc[0][m][n] = __builtin_amdgcn_mfma_f32_16x16x32_bf16(af[m], b0f[n], acc[0][m][n], 0, 0, 0);
        acc[1][m][n] = __builtin_amdgcn_mfma_f32_16x16x32_bf16(af[m], b1f[n], acc[1][m][n], 0, 0, 0);
      }
    }
    __syncthreads();
  }

#pragma unroll
  for (int m = 0; m < MF; ++m) {
#pragma unroll
    for (int j = 0; j < 4; ++j) {
      int grow = m0 + wr * WM + m * 16 + ks * 4 + j;
      float2 ph = phase[grow];
#pragma unroll
      for (int n = 0; n < NF; ++n) {
        int gcol = n0 + wc * WN + n * 16 + lr;
        float v = ph.x * (acc[0][m][n][j] + bias[gcol]) +
                  ph.y * (acc[1][m][n][j] + bias[N + gcol]);
        if (ELU_BF16) {
          v = v > 0.f ? v : (__expf(v) - 1.f);
          ((u16*)out)[(size_t)grow * N + gcol] = f2bf(v);
        } else {
          ((float*)out)[(size_t)grow * N + gcol] = v;
        }
      }
    }
  }
}

extern "C" void kernel_launch(void* const* d_in, const int* in_sizes, int n_in,
                              void* d_out, int out_size, void* d_ws, size_t ws_size,
                              hipStream_t stream) {
  const float* x  = (const float*)d_in[0];
  const float* w1 = (const float*)d_in[1];
  const float* b1 = (const float*)d_in[2];
  const float* w2 = (const float*)d_in[3];
  const float* b2 = (const float*)d_in[4];
  const float* w3 = (const float*)d_in[5];
  const float* b3 = (const float*)d_in[6];
  float* out = (float*)d_out;
  const int B = 32768, DIN = 256, H = 1024, DOUT = 64;

  char* ws = (char*)d_ws;
  u16* W1Ti = (u16*)ws;    ws += (size_t)2 * H * DIN * 2;   // [2048][256]
  u16* W2Ti = (u16*)ws;    ws += (size_t)2 * H * H * 2;     // [2048][1024]
  u16* W3T = (u16*)ws;     ws += (size_t)2 * DOUT * H * 2;  // [2][64][1024]
  float2* phase = (float2*)ws; ws += (size_t)B * 8;
  u16* hx = (u16*)ws;      ws += (size_t)B * DIN * 2;
  u16* h1 = (u16*)ws;      ws += (size_t)B * H * 2;
  u16* h2 = (u16*)ws;      ws += (size_t)B * H * 2;

  prep_x_kernel<<<(B * 128 + 255) / 256, 256, 0, stream>>>(x, hx, phase, B);
  prep_w_int_kernel<<<dim3(DIN / 64, H / 64, 2), 256, 0, stream>>>(w1, W1Ti, DIN, H);
  prep_w_int_kernel<<<dim3(H / 64, H / 64, 2), 256, 0, stream>>>(w2, W2Ti, H, H);
  prep_w_kernel<<<dim3(H / 64, DOUT / 64, 2), 256, 0, stream>>>(w3, W3T, H, DOUT);

  const int nwg = (B / 256) * (2 * H / 256);  // 128 * 8 = 1024
  gemm_ring<true><<<nwg, 512, 0, stream>>>(hx, W1Ti, b1, phase, h1, DIN, 2 * H);
  gemm_ring<true><<<nwg, 512, 0, stream>>>(h1, W2Ti, b2, phase, h2, H, 2 * H);
  gemm_dualmode<128, 64, 64, 32, false>
      <<<dim3(B / 128, DOUT / 64), 256, 0, stream>>>(h2, W3T, b3, phase, out, H, DOUT);
}